// Round 20
// baseline (365.433 us; speedup 1.0000x reference)
//
#include <hip/hip_runtime.h>
#include <hip/hip_bf16.h>

#define B_ 2
#define T_ 2048
#define D_ 1024
#define H_ 16

typedef __attribute__((ext_vector_type(8))) short bf16x8;
typedef __attribute__((ext_vector_type(4))) short bf16x4;
typedef __attribute__((ext_vector_type(4))) float f32x4;

__device__ __forceinline__ unsigned pack_bf16(float x, float y) {
  unsigned xb = __float_as_uint(x), yb = __float_as_uint(y);
  xb += 0x7fffu + ((xb >> 16) & 1u);
  yb += 0x7fffu + ((yb >> 16) & 1u);
  return (xb >> 16) | (yb & 0xffff0000u);
}
__device__ __forceinline__ unsigned cvt_pk(float lo, float hi) {
  unsigned r;
  asm("v_cvt_pk_bf16_f32 %0, %1, %2" : "=v"(r) : "v"(lo), "v"(hi));
  return r;
}
__device__ __forceinline__ unsigned short f2b(float x) {
  unsigned u = __float_as_uint(x);
  u += 0x7fffu + ((u >> 16) & 1u);
  return (unsigned short)(u >> 16);
}
__device__ __forceinline__ float blo(unsigned u) { return __uint_as_float(u << 16); }
__device__ __forceinline__ float bhi(unsigned u) { return __uint_as_float(u & 0xffff0000u); }

__device__ __forceinline__ void gld_lds16(const unsigned short* g, unsigned short* l) {
  __builtin_amdgcn_global_load_lds(
      (const __attribute__((address_space(1))) unsigned int*)g,
      (__attribute__((address_space(3))) unsigned int*)l, 16, 0, 0);
}

// ---------- weight transpose + convert: Wt[n][k] = bf16(W[k][n]), 4 weights ----------
__global__ __launch_bounds__(256) void wtrans(const float* __restrict__ W0, const float* __restrict__ W1,
                                              const float* __restrict__ W2, const float* __restrict__ W3,
                                              unsigned short* __restrict__ T0, unsigned short* __restrict__ T1,
                                              unsigned short* __restrict__ T2, unsigned short* __restrict__ T3) {
  const int z = blockIdx.z;
  const float* W = z == 0 ? W0 : z == 1 ? W1 : z == 2 ? W2 : W3;
  unsigned short* T = z == 0 ? T0 : z == 1 ? T1 : z == 2 ? T2 : T3;
  __shared__ unsigned short t[64][72];
  const int k0 = blockIdx.x << 6, n0 = blockIdx.y << 6;
  const int r = threadIdx.x >> 2, c16 = (threadIdx.x & 3) << 4;
#pragma unroll
  for (int e = 0; e < 4; ++e) {
    const float4 v = *(const float4*)&W[(size_t)(k0 + r) * 1024 + n0 + c16 + e * 4];
    t[r][c16 + e * 4 + 0] = f2b(v.x);
    t[r][c16 + e * 4 + 1] = f2b(v.y);
    t[r][c16 + e * 4 + 2] = f2b(v.z);
    t[r][c16 + e * 4 + 3] = f2b(v.w);
  }
  __syncthreads();
  unsigned short o[16];
#pragma unroll
  for (int e = 0; e < 16; ++e) o[e] = t[c16 + e][r];
  unsigned short* dst = &T[(size_t)(n0 + r) * 1024 + k0 + c16];
  *(uint4*)&dst[0] = *(uint4*)&o[0];
  *(uint4*)&dst[8] = *(uint4*)&o[8];
}

// ---------- x fp32 -> bf16 ----------
__global__ __launch_bounds__(256) void xconv(const float* __restrict__ x, unsigned short* __restrict__ xb) {
  const int i = (blockIdx.x * 256 + threadIdx.x) * 8;
  const float4 a = *(const float4*)&x[i];
  const float4 b = *(const float4*)&x[i + 4];
  uint4 o;
  o.x = pack_bf16(a.x, a.y);
  o.y = pack_bf16(a.z, a.w);
  o.z = pack_bf16(b.x, b.y);
  o.w = pack_bf16(b.z, b.w);
  *(uint4*)&xb[i] = o;
}

// ---------- bf16 MFMA GEMM: Y = A[M,1024] @ Bt[n][k]^T + bias ----------
template <bool BF16OUT>
__global__ __launch_bounds__(256) void gemm_mfma(const unsigned short* __restrict__ A,
                                                 const unsigned short* __restrict__ B0,
                                                 const unsigned short* __restrict__ B1,
                                                 const unsigned short* __restrict__ B2,
                                                 const float* __restrict__ bi0, const float* __restrict__ bi1,
                                                 const float* __restrict__ bi2,
                                                 void* __restrict__ Y0, void* __restrict__ Y1,
                                                 void* __restrict__ Y2) {
  const int z = blockIdx.z;
  const unsigned short* Bt = z == 0 ? B0 : z == 1 ? B1 : B2;
  const float* bias = z == 0 ? bi0 : z == 1 ? bi1 : bi2;
  void* Y = z == 0 ? Y0 : z == 1 ? Y1 : Y2;
  __shared__ unsigned short As[8192];
  __shared__ unsigned short Bs[8192];
  const int tid = threadIdx.x;
  const int m0 = blockIdx.y << 7, n0 = blockIdx.x << 7;
  const int w = tid >> 6, l = tid & 63, g = l >> 4, c = l & 15;
  const int wm = (w >> 1) << 6, wn = (w & 1) << 6;
  const int srow = tid >> 3;
  const int skel = ((tid & 7) ^ (srow & 7)) << 3;
  const unsigned short* ga = &A[(size_t)(m0 + srow) * 1024 + skel];
  const unsigned short* gb = &Bt[(size_t)(n0 + srow) * 1024 + skel];
  unsigned short* la = &As[tid << 3];
  unsigned short* lb = &Bs[tid << 3];
  f32x4 acc[4][4];
#pragma unroll
  for (int i = 0; i < 4; ++i)
#pragma unroll
    for (int j = 0; j < 4; ++j) acc[i][j] = {0.f, 0.f, 0.f, 0.f};
  for (int k0 = 0; k0 < 1024; k0 += 64) {
    __syncthreads();
#pragma unroll
    for (int a = 0; a < 4; ++a) {
      gld_lds16(ga + (size_t)(a << 5) * 1024 + k0, la + (a << 11));
      gld_lds16(gb + (size_t)(a << 5) * 1024 + k0, lb + (a << 11));
    }
    __syncthreads();
#pragma unroll
    for (int kc = 0; kc < 2; ++kc) {
      bf16x8 af[4], bfr[4];
#pragma unroll
      for (int mf = 0; mf < 4; ++mf) {
        const int m = wm + (mf << 4) + c;
        af[mf] = *(const bf16x8*)&As[((m << 6) + (kc << 5) + (g << 3)) ^ ((m & 7) << 3)];
      }
#pragma unroll
      for (int nf = 0; nf < 4; ++nf) {
        const int n = wn + (nf << 4) + c;
        bfr[nf] = *(const bf16x8*)&Bs[((n << 6) + (kc << 5) + (g << 3)) ^ ((n & 7) << 3)];
      }
#pragma unroll
      for (int mf = 0; mf < 4; ++mf)
#pragma unroll
        for (int nf = 0; nf < 4; ++nf)
          acc[mf][nf] = __builtin_amdgcn_mfma_f32_16x16x32_bf16(af[mf], bfr[nf], acc[mf][nf], 0, 0, 0);
    }
  }
#pragma unroll
  for (int nf = 0; nf < 4; ++nf) {
    const int n = n0 + wn + (nf << 4) + c;
    const float bb = bias[n];
#pragma unroll
    for (int mf = 0; mf < 4; ++mf) {
      const int mrow = m0 + wm + (mf << 4) + (g << 2);
#pragma unroll
      for (int r = 0; r < 4; ++r) {
        const float val = acc[mf][nf][r] + bb;
        if (BF16OUT)
          ((unsigned short*)Y)[((size_t)(mrow + r) << 10) + n] = f2b(val);
        else
          ((float*)Y)[((size_t)(mrow + r) << 10) + n] = val;
      }
    }
  }
}

// ---------- V-projection GEMM with fused transpose: Vt[b][d][t] written directly ----------
__global__ __launch_bounds__(256) void gemm_vt(const unsigned short* __restrict__ A,
                                               const unsigned short* __restrict__ Bt,
                                               const float* __restrict__ bias,
                                               unsigned short* __restrict__ Vt) {
  __shared__ unsigned short As[8192];
  __shared__ unsigned short Bs[8192];
  __shared__ unsigned short sm[128][136];
  const int tid = threadIdx.x;
  const int m0 = blockIdx.y << 7, n0 = blockIdx.x << 7;
  const int w = tid >> 6, l = tid & 63, g = l >> 4, c = l & 15;
  const int wm = (w >> 1) << 6, wn = (w & 1) << 6;
  const int srow = tid >> 3;
  const int skel = ((tid & 7) ^ (srow & 7)) << 3;
  const unsigned short* ga = &A[(size_t)(m0 + srow) * 1024 + skel];
  const unsigned short* gb = &Bt[(size_t)(n0 + srow) * 1024 + skel];
  unsigned short* la = &As[tid << 3];
  unsigned short* lb = &Bs[tid << 3];
  f32x4 acc[4][4];
#pragma unroll
  for (int i = 0; i < 4; ++i)
#pragma unroll
    for (int j = 0; j < 4; ++j) acc[i][j] = {0.f, 0.f, 0.f, 0.f};
  for (int k0 = 0; k0 < 1024; k0 += 64) {
    __syncthreads();
#pragma unroll
    for (int a = 0; a < 4; ++a) {
      gld_lds16(ga + (size_t)(a << 5) * 1024 + k0, la + (a << 11));
      gld_lds16(gb + (size_t)(a << 5) * 1024 + k0, lb + (a << 11));
    }
    __syncthreads();
#pragma unroll
    for (int kc = 0; kc < 2; ++kc) {
      bf16x8 af[4], bfr[4];
#pragma unroll
      for (int mf = 0; mf < 4; ++mf) {
        const int m = wm + (mf << 4) + c;
        af[mf] = *(const bf16x8*)&As[((m << 6) + (kc << 5) + (g << 3)) ^ ((m & 7) << 3)];
      }
#pragma unroll
      for (int nf = 0; nf < 4; ++nf) {
        const int n = wn + (nf << 4) + c;
        bfr[nf] = *(const bf16x8*)&Bs[((n << 6) + (kc << 5) + (g << 3)) ^ ((n & 7) << 3)];
      }
#pragma unroll
      for (int mf = 0; mf < 4; ++mf)
#pragma unroll
        for (int nf = 0; nf < 4; ++nf)
          acc[mf][nf] = __builtin_amdgcn_mfma_f32_16x16x32_bf16(af[mf], bfr[nf], acc[mf][nf], 0, 0, 0);
    }
  }
  __syncthreads();
#pragma unroll
  for (int nf = 0; nf < 4; ++nf) {
    const int nl = wn + (nf << 4) + c;
    const float bb = bias[n0 + nl];
#pragma unroll
    for (int mf = 0; mf < 4; ++mf) {
      const int ml = wm + (mf << 4) + (g << 2);
      uint2 o;
      o.x = pack_bf16(acc[mf][nf][0] + bb, acc[mf][nf][1] + bb);
      o.y = pack_bf16(acc[mf][nf][2] + bb, acc[mf][nf][3] + bb);
      *(uint2*)&sm[nl][ml] = o;
    }
  }
  __syncthreads();
  const int bb2 = m0 >> 11, mr0 = m0 & 2047;
#pragma unroll
  for (int it = 0; it < 8; ++it) {
    const int u = tid + (it << 8);
    const int ns = u >> 4, mc = (u & 15) << 3;
    *(uint4*)&Vt[(((size_t)((bb2 << 10) + n0 + ns)) << 11) + mr0 + mc] = *(const uint4*)&sm[ns][mc];
  }
}

// ---------- fused block-sum + suffix: Suf[b][t][d] = sum_{j >= 32t} V[b][j][d] ----------
__global__ __launch_bounds__(256) void vsuf(const unsigned short* __restrict__ Vt,
                                            float* __restrict__ Suf) {
  const int b = blockIdx.x >> 2;
  const int d = ((blockIdx.x & 3) << 8) + threadIdx.x;
  const unsigned short* vr = &Vt[((size_t)((b << 10) + d)) << 11];
  float s = 0.f;
  Suf[((size_t)(b * 65 + 64) << 10) + d] = 0.f;
  for (int t = 63; t >= 0; --t) {
    float ts = 0.f;
#pragma unroll
    for (int qq = 0; qq < 4; ++qq) {
      const uint2 v0 = *(const uint2*)&vr[(t << 5) + (qq << 3)];
      const uint2 v1 = *(const uint2*)&vr[(t << 5) + (qq << 3) + 4];
      ts += blo(v0.x) + bhi(v0.x) + blo(v0.y) + bhi(v0.y);
      ts += blo(v1.x) + bhi(v1.x) + blo(v1.y) + bhi(v1.y);
    }
    s += ts;
    Suf[((size_t)(b * 65 + t) << 10) + d] = s;
  }
}

// ---------- attention v20: ds_add_f32 Sigma-exchange + cvt_pk packs ----------
// v19 pipeline (16-j steps, double-buffered K/V, split barriers). The denominator
// exchange uses native LDS float atomics into a 4 KB double-buffered SxA: each lane
// adds its f32x4 partial (8-way per address), BAR1 (lgkm-only) publishes, each lane
// reads ONE 16 B sum (was 128 B), wave hp0 zeroes the next buffer before BAR2.
__global__ __launch_bounds__(1024, 4) void attn_v20(const unsigned short* __restrict__ Qb,
                                                    const unsigned short* __restrict__ Kb,
                                                    const unsigned short* __restrict__ Vt,
                                                    unsigned short* __restrict__ P0,
                                                    unsigned short* __restrict__ P1,
                                                    unsigned short* __restrict__ P2,
                                                    unsigned short* __restrict__ P3) {
  __shared__ unsigned short Ks[2][16 * 1024];  // 2 x 32 KB
  __shared__ unsigned short Vs[2][1024 * 16];  // 2 x 32 KB
  __shared__ float SxA[2][2][64][4];           // 4 KB atomic denominators

  const int combo = blockIdx.x;
  const int b = combo & 1, s = combo >> 1;
  const int qy = 63 - blockIdx.y;
  const int tid = threadIdx.x;
  const int w = tid >> 6, l = tid & 63, g = l >> 4, c = l & 15;
  const int isub = w >> 3, hp = w & 7;
  const float SC = 0.04508422f;  // log2(e)/32
  unsigned short* AOp = s == 0 ? P0 : s == 1 ? P1 : s == 2 ? P2 : P3;

  const int krow0 = tid >> 7, kc8 = tid & 127;
  const int kscc0 = kc8 ^ (krow0 & 7);
  const int krow1 = krow0 + 8;
  const int kscc1 = kc8 ^ (krow1 & 7);
  const unsigned short* kp0 = &Kb[(((size_t)((b << 11) + krow0)) << 10) + (kscc0 << 3)];
  const unsigned short* kp1 = &Kb[(((size_t)((b << 11) + krow1)) << 10) + (kscc1 << 3)];
  const int vd0 = tid >> 1, vjc = tid & 1;
  const int vjo0 = ((vjc << 1) ^ (((vd0 >> 2) & 1) << 1)) << 2;
  const int vd1 = vd0 + 512;
  const int vjo1 = ((vjc << 1) ^ (((vd1 >> 2) & 1) << 1)) << 2;
  const unsigned short* vp0 = &Vt[(((size_t)((b << 10) + vd0)) << 11) + vjo0];
  const unsigned short* vp1 = &Vt[(((size_t)((b << 10) + vd1)) << 11) + vjo1];

#pragma unroll
  for (int ph = 0; ph < 2; ++ph) {
    const int q = ph ? (63 - qy) : qy;
    const int nt16 = (q + 1) << 1;
    const int i0w = (q << 5) + (isub << 4);
    const int ib = i0w + c;

    const unsigned short* qbase =
        &Qb[((size_t)((b << 11) + i0w + c) << 10) + (hp << 7) + (g << 3)];
    bf16x8 qf[4];
    qf[0] = *(const bf16x8*)&qbase[0];
    qf[1] = *(const bf16x8*)&qbase[32];
    qf[2] = *(const bf16x8*)&qbase[64];
    qf[3] = *(const bf16x8*)&qbase[96];

    f32x4 acc[2][4];
#pragma unroll
    for (int hh = 0; hh < 2; ++hh)
#pragma unroll
      for (int cc = 0; cc < 4; ++cc) acc[hh][cc] = {0.f, 0.f, 0.f, 0.f};

#pragma unroll
    for (int e = 0; e < 2; ++e) {
      const int eh = e ? (7 - s) : s;
      const int lo = eh << 4;
      const int hi = (lo + 16) < nt16 ? (lo + 16) : nt16;
      if (lo >= hi) continue;

      // zero both atomic buffers for this range (fenced by the prologue barrier)
      if (hp == 0) {
        *(f32x4*)&SxA[0][isub][l][0] = (f32x4){0.f, 0.f, 0.f, 0.f};
        *(f32x4*)&SxA[1][isub][l][0] = (f32x4){0.f, 0.f, 0.f, 0.f};
      }
      {
        const size_t ko = ((size_t)lo << 14);
        gld_lds16(kp0 + ko, &Ks[0][tid << 3]);
        gld_lds16(kp1 + ko, &Ks[0][(tid + 1024) << 3]);
        const int jo = lo << 4;
        gld_lds16(vp0 + jo, &Vs[0][tid << 3]);
        gld_lds16(vp1 + jo, &Vs[0][(tid + 1024) << 3]);
      }
      __syncthreads();

      int sxb = 0;
      for (int ts = lo; ts < hi; ++ts) {
        const int cur = (ts - lo) & 1;
        if (ts + 1 < hi) {
          const size_t ko = ((size_t)(ts + 1) << 14);
          gld_lds16(kp0 + ko, &Ks[cur ^ 1][tid << 3]);
          gld_lds16(kp1 + ko, &Ks[cur ^ 1][(tid + 1024) << 3]);
          const int jo = (ts + 1) << 4;
          gld_lds16(vp0 + jo, &Vs[cur ^ 1][tid << 3]);
          gld_lds16(vp1 + jo, &Vs[cur ^ 1][(tid + 1024) << 3]);
        }
        const int j0 = ts << 4;
        const int kx = c & 7;
        f32x4 ex[2];
        f32x4 ps = {0.f, 0.f, 0.f, 0.f};
#pragma unroll
        for (int hh = 0; hh < 2; ++hh) {
          const int hc = ((hp << 1) + hh) << 3;
          const bf16x8 k0 = *(const bf16x8*)&Ks[cur][((c << 7) + ((hc + g) ^ kx)) << 3];
          const bf16x8 k1 = *(const bf16x8*)&Ks[cur][((c << 7) + ((hc + 4 + g) ^ kx)) << 3];
          f32x4 a = {0.f, 0.f, 0.f, 0.f};
          a = __builtin_amdgcn_mfma_f32_16x16x32_bf16(k0, qf[2 * hh], a, 0, 0, 0);
          a = __builtin_amdgcn_mfma_f32_16x16x32_bf16(k1, qf[2 * hh + 1], a, 0, 0, 0);
#pragma unroll
          for (int r = 0; r < 4; ++r) ex[hh][r] = exp2f(a[r] * SC);
          ps += ex[hh];
        }
#pragma unroll
        for (int r = 0; r < 4; ++r) unsafeAtomicAdd(&SxA[sxb][isub][l][r], ps[r]);
        // BAR1: fence LDS (atomics) only — staging stays in flight
        asm volatile("s_waitcnt lgkmcnt(0)" ::: "memory");
        __builtin_amdgcn_s_barrier();
        __builtin_amdgcn_sched_barrier(0);
        const f32x4 sum = *(const f32x4*)&SxA[sxb][isub][l][0];
        f32x4 inv;
#pragma unroll
        for (int r = 0; r < 4; ++r) inv[r] = __builtin_amdgcn_rcpf(sum[r]);
        // zero the other buffer for step ts+1 (its atomics start after BAR2)
        if (hp == 0) *(f32x4*)&SxA[sxb ^ 1][isub][l][0] = (f32x4){0.f, 0.f, 0.f, 0.f};
        sxb ^= 1;
        float wv[2][4];
        if (j0 + 15 <= i0w) {
#pragma unroll
          for (int hh = 0; hh < 2; ++hh)
#pragma unroll
            for (int r = 0; r < 4; ++r) wv[hh][r] = ex[hh][r] * inv[r];
        } else {
          const int jb = j0 + (g << 2);
#pragma unroll
          for (int hh = 0; hh < 2; ++hh)
#pragma unroll
            for (int r = 0; r < 4; ++r)
              wv[hh][r] = (jb + r > ib) ? 0.0625f : ex[hh][r] * inv[r];
        }
#pragma unroll
        for (int hh = 0; hh < 2; ++hh) {
          union { bf16x4 v; unsigned u[2]; } pa;
          pa.u[0] = cvt_pk(wv[hh][0], wv[hh][1]);
          pa.u[1] = cvt_pk(wv[hh][2], wv[hh][3]);
#pragma unroll
          for (int cc = 0; cc < 4; ++cc) {
            const int d = (((hp << 1) + hh) << 6) + (cc << 4) + c;
            const int up = g ^ (((d >> 2) & 1) << 1);
            union { bf16x4 v; unsigned u[2]; } vf;
            *(uint2*)&vf = *(const uint2*)&Vs[cur][(d << 4) + (up << 2)];
            acc[hh][cc] =
                __builtin_amdgcn_mfma_f32_16x16x16bf16_1k(pa.v, vf.v, acc[hh][cc], 0, 0, 0);
          }
        }
        __syncthreads();  // BAR2: full drain before buffer reuse
      }
    }
#pragma unroll
    for (int hh = 0; hh < 2; ++hh)
#pragma unroll
      for (int cc = 0; cc < 4; ++cc) {
        const int d = (((hp << 1) + hh) << 6) + (cc << 4) + c;
#pragma unroll
        for (int r = 0; r < 4; ++r)
          AOp[((size_t)((b << 11) + i0w + (g << 2) + r) << 10) + d] = f2b(acc[hh][cc][r]);
      }
  }
}

// ---------- sum 4 bf16 partials + (1/16)*suffix -> bf16 ----------
__global__ __launch_bounds__(256) void aocvt(const unsigned short* __restrict__ P0,
                                             const unsigned short* __restrict__ P1,
                                             const unsigned short* __restrict__ P2,
                                             const unsigned short* __restrict__ P3,
                                             const float* __restrict__ Suf,
                                             unsigned short* __restrict__ AOb) {
  const int i = (blockIdx.x * 256 + threadIdx.x) << 3;
  const int m = i >> 10;
  const int b = m >> 11;
  const int sufidx = ((m & 2047) >> 5) + 1;
  const int d0 = i & 1023;
  const float* sp = &Suf[((size_t)(b * 65 + sufidx) << 10) + d0];
  const uint4 v0 = *(const uint4*)&P0[i];
  const uint4 v1 = *(const uint4*)&P1[i];
  const uint4 v2 = *(const uint4*)&P2[i];
  const uint4 v3 = *(const uint4*)&P3[i];
  const float4 s0 = *(const float4*)&sp[0];
  const float4 s1 = *(const float4*)&sp[4];
  uint4 o;
  o.x = pack_bf16(blo(v0.x) + blo(v1.x) + blo(v2.x) + blo(v3.x) + 0.0625f * s0.x,
                  bhi(v0.x) + bhi(v1.x) + bhi(v2.x) + bhi(v3.x) + 0.0625f * s0.y);
  o.y = pack_bf16(blo(v0.y) + blo(v1.y) + blo(v2.y) + blo(v3.y) + 0.0625f * s0.z,
                  bhi(v0.y) + bhi(v1.y) + bhi(v2.y) + bhi(v3.y) + 0.0625f * s0.w);
  o.z = pack_bf16(blo(v0.z) + blo(v1.z) + blo(v2.z) + blo(v3.z) + 0.0625f * s1.x,
                  bhi(v0.z) + bhi(v1.z) + bhi(v2.z) + bhi(v3.z) + 0.0625f * s1.y);
  o.w = pack_bf16(blo(v0.w) + blo(v1.w) + blo(v2.w) + blo(v3.w) + 0.0625f * s1.z,
                  bhi(v0.w) + bhi(v1.w) + bhi(v2.w) + bhi(v3.w) + 0.0625f * s1.w);
  *(uint4*)&AOb[i] = o;
}

extern "C" void kernel_launch(void* const* d_in, const int* in_sizes, int n_in,
                              void* d_out, int out_size, void* d_ws, size_t ws_size,
                              hipStream_t stream) {
  (void)in_sizes; (void)n_in; (void)out_size; (void)ws_size;
  const float* x = (const float*)d_in[0];
  const float* Wq = (const float*)d_in[1];
  const float* bq = (const float*)d_in[2];
  const float* Wk = (const float*)d_in[3];
  const float* bk = (const float*)d_in[4];
  const float* Wv = (const float*)d_in[5];
  const float* bv = (const float*)d_in[6];
  const float* Wo = (const float*)d_in[7];
  const float* bo = (const float*)d_in[8];
  float* out = (float*)d_out;
  char* ws = (char*)d_ws;

  const size_t MB = 1024 * 1024;
  unsigned short* xb  = (unsigned short*)(ws);            // 0-8MB; = AOP0 after projections
  unsigned short* Qb  = (unsigned short*)(ws + 8 * MB);   // 8-16; = AOb after attn
  unsigned short* Kb  = (unsigned short*)(ws + 16 * MB);  // 16-24
  unsigned short* AOP1 = (unsigned short*)(ws + 24 * MB); // 24-32
  unsigned short* Vt  = (unsigned short*)(ws + 32 * MB);  // 32-40
  unsigned short* Wqt = (unsigned short*)(ws + 40 * MB);  // 40-42; Suf overlays after proj
  unsigned short* Wkt = (unsigned short*)(ws + 42 * MB);  // 42-44
  unsigned short* Wvt = (unsigned short*)(ws + 44 * MB);  // 44-46
  unsigned short* Wot = (unsigned short*)(ws + 46 * MB);  // 46-48
  unsigned short* AOP2 = (unsigned short*)(ws + 48 * MB); // 48-56
  unsigned short* AOP3 = (unsigned short*)(ws + 56 * MB); // 56-64
  float* Suf = (float*)(ws + 40 * MB);                    // 532 KB (over dead Wqt)
  unsigned short* AOP0 = xb;
  unsigned short* AOb = Qb;

  hipLaunchKernelGGL(wtrans, dim3(16, 16, 4), dim3(256), 0, stream,
                     Wq, Wk, Wv, Wo, Wqt, Wkt, Wvt, Wot);
  hipLaunchKernelGGL(xconv, dim3(2048), dim3(256), 0, stream, x, xb);
  hipLaunchKernelGGL((gemm_mfma<true>), dim3(8, 32, 2), dim3(256), 0, stream,
                     xb, Wqt, Wkt, Wkt, bq, bk, bk, (void*)Qb, (void*)Kb, (void*)Kb);
  hipLaunchKernelGGL(gemm_vt, dim3(8, 32), dim3(256), 0, stream, xb, Wvt, bv, Vt);
  hipLaunchKernelGGL(vsuf, dim3(8), dim3(256), 0, stream, Vt, Suf);
  hipLaunchKernelGGL(attn_v20, dim3(8, 32), dim3(1024), 0, stream,
                     Qb, Kb, Vt, AOP0, AOP1, AOP2, AOP3);
  hipLaunchKernelGGL(aocvt, dim3(2048), dim3(256), 0, stream,
                     AOP0, AOP1, AOP2, AOP3, Suf, AOb);
  hipLaunchKernelGGL((gemm_mfma<false>), dim3(8, 32, 1), dim3(256), 0, stream,
                     AOb, Wot, Wot, Wot, bo, bo, bo, (void*)out, (void*)out, (void*)out);
}

// Round 21
// 216.244 us; speedup vs baseline: 1.6899x; 1.6899x over previous
//
#include <hip/hip_runtime.h>
#include <hip/hip_bf16.h>

#define B_ 2
#define T_ 2048
#define D_ 1024
#define H_ 16

typedef __attribute__((ext_vector_type(8))) short bf16x8;
typedef __attribute__((ext_vector_type(4))) short bf16x4;
typedef __attribute__((ext_vector_type(4))) float f32x4;

__device__ __forceinline__ unsigned pack_bf16(float x, float y) {
  unsigned xb = __float_as_uint(x), yb = __float_as_uint(y);
  xb += 0x7fffu + ((xb >> 16) & 1u);
  yb += 0x7fffu + ((yb >> 16) & 1u);
  return (xb >> 16) | (yb & 0xffff0000u);
}
__device__ __forceinline__ unsigned short f2b(float x) {
  unsigned u = __float_as_uint(x);
  u += 0x7fffu + ((u >> 16) & 1u);
  return (unsigned short)(u >> 16);
}
__device__ __forceinline__ float blo(unsigned u) { return __uint_as_float(u << 16); }
__device__ __forceinline__ float bhi(unsigned u) { return __uint_as_float(u & 0xffff0000u); }

__device__ __forceinline__ void gld_lds16(const unsigned short* g, unsigned short* l) {
  __builtin_amdgcn_global_load_lds(
      (const __attribute__((address_space(1))) unsigned int*)g,
      (__attribute__((address_space(3))) unsigned int*)l, 16, 0, 0);
}

// ---------- weight transpose + convert: Wt[n][k] = bf16(W[k][n]), 4 weights ----------
__global__ __launch_bounds__(256) void wtrans(const float* __restrict__ W0, const float* __restrict__ W1,
                                              const float* __restrict__ W2, const float* __restrict__ W3,
                                              unsigned short* __restrict__ T0, unsigned short* __restrict__ T1,
                                              unsigned short* __restrict__ T2, unsigned short* __restrict__ T3) {
  const int z = blockIdx.z;
  const float* W = z == 0 ? W0 : z == 1 ? W1 : z == 2 ? W2 : W3;
  unsigned short* T = z == 0 ? T0 : z == 1 ? T1 : z == 2 ? T2 : T3;
  __shared__ unsigned short t[64][72];
  const int k0 = blockIdx.x << 6, n0 = blockIdx.y << 6;
  const int r = threadIdx.x >> 2, c16 = (threadIdx.x & 3) << 4;
#pragma unroll
  for (int e = 0; e < 4; ++e) {
    const float4 v = *(const float4*)&W[(size_t)(k0 + r) * 1024 + n0 + c16 + e * 4];
    t[r][c16 + e * 4 + 0] = f2b(v.x);
    t[r][c16 + e * 4 + 1] = f2b(v.y);
    t[r][c16 + e * 4 + 2] = f2b(v.z);
    t[r][c16 + e * 4 + 3] = f2b(v.w);
  }
  __syncthreads();
  unsigned short o[16];
#pragma unroll
  for (int e = 0; e < 16; ++e) o[e] = t[c16 + e][r];
  unsigned short* dst = &T[(size_t)(n0 + r) * 1024 + k0 + c16];
  *(uint4*)&dst[0] = *(uint4*)&o[0];
  *(uint4*)&dst[8] = *(uint4*)&o[8];
}

// ---------- x fp32 -> bf16 ----------
__global__ __launch_bounds__(256) void xconv(const float* __restrict__ x, unsigned short* __restrict__ xb) {
  const int i = (blockIdx.x * 256 + threadIdx.x) * 8;
  const float4 a = *(const float4*)&x[i];
  const float4 b = *(const float4*)&x[i + 4];
  uint4 o;
  o.x = pack_bf16(a.x, a.y);
  o.y = pack_bf16(a.z, a.w);
  o.z = pack_bf16(b.x, b.y);
  o.w = pack_bf16(b.z, b.w);
  *(uint4*)&xb[i] = o;
}

// ---------- bf16 MFMA GEMM: Y = A[M,1024] @ Bt[n][k]^T + bias ----------
template <bool BF16OUT>
__global__ __launch_bounds__(256) void gemm_mfma(const unsigned short* __restrict__ A,
                                                 const unsigned short* __restrict__ B0,
                                                 const unsigned short* __restrict__ B1,
                                                 const unsigned short* __restrict__ B2,
                                                 const float* __restrict__ bi0, const float* __restrict__ bi1,
                                                 const float* __restrict__ bi2,
                                                 void* __restrict__ Y0, void* __restrict__ Y1,
                                                 void* __restrict__ Y2) {
  const int z = blockIdx.z;
  const unsigned short* Bt = z == 0 ? B0 : z == 1 ? B1 : B2;
  const float* bias = z == 0 ? bi0 : z == 1 ? bi1 : bi2;
  void* Y = z == 0 ? Y0 : z == 1 ? Y1 : Y2;
  __shared__ unsigned short As[8192];
  __shared__ unsigned short Bs[8192];
  const int tid = threadIdx.x;
  const int m0 = blockIdx.y << 7, n0 = blockIdx.x << 7;
  const int w = tid >> 6, l = tid & 63, g = l >> 4, c = l & 15;
  const int wm = (w >> 1) << 6, wn = (w & 1) << 6;
  const int srow = tid >> 3;
  const int skel = ((tid & 7) ^ (srow & 7)) << 3;
  const unsigned short* ga = &A[(size_t)(m0 + srow) * 1024 + skel];
  const unsigned short* gb = &Bt[(size_t)(n0 + srow) * 1024 + skel];
  unsigned short* la = &As[tid << 3];
  unsigned short* lb = &Bs[tid << 3];
  f32x4 acc[4][4];
#pragma unroll
  for (int i = 0; i < 4; ++i)
#pragma unroll
    for (int j = 0; j < 4; ++j) acc[i][j] = {0.f, 0.f, 0.f, 0.f};
  for (int k0 = 0; k0 < 1024; k0 += 64) {
    __syncthreads();
#pragma unroll
    for (int a = 0; a < 4; ++a) {
      gld_lds16(ga + (size_t)(a << 5) * 1024 + k0, la + (a << 11));
      gld_lds16(gb + (size_t)(a << 5) * 1024 + k0, lb + (a << 11));
    }
    __syncthreads();
#pragma unroll
    for (int kc = 0; kc < 2; ++kc) {
      bf16x8 af[4], bfr[4];
#pragma unroll
      for (int mf = 0; mf < 4; ++mf) {
        const int m = wm + (mf << 4) + c;
        af[mf] = *(const bf16x8*)&As[((m << 6) + (kc << 5) + (g << 3)) ^ ((m & 7) << 3)];
      }
#pragma unroll
      for (int nf = 0; nf < 4; ++nf) {
        const int n = wn + (nf << 4) + c;
        bfr[nf] = *(const bf16x8*)&Bs[((n << 6) + (kc << 5) + (g << 3)) ^ ((n & 7) << 3)];
      }
#pragma unroll
      for (int mf = 0; mf < 4; ++mf)
#pragma unroll
        for (int nf = 0; nf < 4; ++nf)
          acc[mf][nf] = __builtin_amdgcn_mfma_f32_16x16x32_bf16(af[mf], bfr[nf], acc[mf][nf], 0, 0, 0);
    }
  }
#pragma unroll
  for (int nf = 0; nf < 4; ++nf) {
    const int n = n0 + wn + (nf << 4) + c;
    const float bb = bias[n];
#pragma unroll
    for (int mf = 0; mf < 4; ++mf) {
      const int mrow = m0 + wm + (mf << 4) + (g << 2);
#pragma unroll
      for (int r = 0; r < 4; ++r) {
        const float val = acc[mf][nf][r] + bb;
        if (BF16OUT)
          ((unsigned short*)Y)[((size_t)(mrow + r) << 10) + n] = f2b(val);
        else
          ((float*)Y)[((size_t)(mrow + r) << 10) + n] = val;
      }
    }
  }
}

// ---------- V-projection GEMM with fused transpose: Vt[b][d][t] written directly ----------
__global__ __launch_bounds__(256) void gemm_vt(const unsigned short* __restrict__ A,
                                               const unsigned short* __restrict__ Bt,
                                               const float* __restrict__ bias,
                                               unsigned short* __restrict__ Vt) {
  __shared__ unsigned short As[8192];
  __shared__ unsigned short Bs[8192];
  __shared__ unsigned short sm[128][136];
  const int tid = threadIdx.x;
  const int m0 = blockIdx.y << 7, n0 = blockIdx.x << 7;
  const int w = tid >> 6, l = tid & 63, g = l >> 4, c = l & 15;
  const int wm = (w >> 1) << 6, wn = (w & 1) << 6;
  const int srow = tid >> 3;
  const int skel = ((tid & 7) ^ (srow & 7)) << 3;
  const unsigned short* ga = &A[(size_t)(m0 + srow) * 1024 + skel];
  const unsigned short* gb = &Bt[(size_t)(n0 + srow) * 1024 + skel];
  unsigned short* la = &As[tid << 3];
  unsigned short* lb = &Bs[tid << 3];
  f32x4 acc[4][4];
#pragma unroll
  for (int i = 0; i < 4; ++i)
#pragma unroll
    for (int j = 0; j < 4; ++j) acc[i][j] = {0.f, 0.f, 0.f, 0.f};
  for (int k0 = 0; k0 < 1024; k0 += 64) {
    __syncthreads();
#pragma unroll
    for (int a = 0; a < 4; ++a) {
      gld_lds16(ga + (size_t)(a << 5) * 1024 + k0, la + (a << 11));
      gld_lds16(gb + (size_t)(a << 5) * 1024 + k0, lb + (a << 11));
    }
    __syncthreads();
#pragma unroll
    for (int kc = 0; kc < 2; ++kc) {
      bf16x8 af[4], bfr[4];
#pragma unroll
      for (int mf = 0; mf < 4; ++mf) {
        const int m = wm + (mf << 4) + c;
        af[mf] = *(const bf16x8*)&As[((m << 6) + (kc << 5) + (g << 3)) ^ ((m & 7) << 3)];
      }
#pragma unroll
      for (int nf = 0; nf < 4; ++nf) {
        const int n = wn + (nf << 4) + c;
        bfr[nf] = *(const bf16x8*)&Bs[((n << 6) + (kc << 5) + (g << 3)) ^ ((n & 7) << 3)];
      }
#pragma unroll
      for (int mf = 0; mf < 4; ++mf)
#pragma unroll
        for (int nf = 0; nf < 4; ++nf)
          acc[mf][nf] = __builtin_amdgcn_mfma_f32_16x16x32_bf16(af[mf], bfr[nf], acc[mf][nf], 0, 0, 0);
    }
  }
  __syncthreads();
#pragma unroll
  for (int nf = 0; nf < 4; ++nf) {
    const int nl = wn + (nf << 4) + c;
    const float bb = bias[n0 + nl];
#pragma unroll
    for (int mf = 0; mf < 4; ++mf) {
      const int ml = wm + (mf << 4) + (g << 2);
      uint2 o;
      o.x = pack_bf16(acc[mf][nf][0] + bb, acc[mf][nf][1] + bb);
      o.y = pack_bf16(acc[mf][nf][2] + bb, acc[mf][nf][3] + bb);
      *(uint2*)&sm[nl][ml] = o;
    }
  }
  __syncthreads();
  const int bb2 = m0 >> 11, mr0 = m0 & 2047;
#pragma unroll
  for (int it = 0; it < 8; ++it) {
    const int u = tid + (it << 8);
    const int ns = u >> 4, mc = (u & 15) << 3;
    *(uint4*)&Vt[(((size_t)((bb2 << 10) + n0 + ns)) << 11) + mr0 + mc] = *(const uint4*)&sm[ns][mc];
  }
}

// ---------- fused block-sum + suffix: Suf[b][t][d] = sum_{j >= 32t} V[b][j][d] ----------
__global__ __launch_bounds__(256) void vsuf(const unsigned short* __restrict__ Vt,
                                            float* __restrict__ Suf) {
  const int b = blockIdx.x >> 2;
  const int d = ((blockIdx.x & 3) << 8) + threadIdx.x;
  const unsigned short* vr = &Vt[((size_t)((b << 10) + d)) << 11];
  float s = 0.f;
  Suf[((size_t)(b * 65 + 64) << 10) + d] = 0.f;
  for (int t = 63; t >= 0; --t) {
    float ts = 0.f;
#pragma unroll
    for (int qq = 0; qq < 4; ++qq) {
      const uint2 v0 = *(const uint2*)&vr[(t << 5) + (qq << 3)];
      const uint2 v1 = *(const uint2*)&vr[(t << 5) + (qq << 3) + 4];
      ts += blo(v0.x) + bhi(v0.x) + blo(v0.y) + bhi(v0.y);
      ts += blo(v1.x) + bhi(v1.x) + blo(v1.y) + bhi(v1.y);
    }
    s += ts;
    Suf[((size_t)(b * 65 + t) << 10) + d] = s;
  }
}

// ---------- attention v21 (= v19): split-barrier double-buffered pipeline ----------
__global__ __launch_bounds__(1024, 4) void attn_v21(const unsigned short* __restrict__ Qb,
                                                    const unsigned short* __restrict__ Kb,
                                                    const unsigned short* __restrict__ Vt,
                                                    unsigned short* __restrict__ P0,
                                                    unsigned short* __restrict__ P1,
                                                    unsigned short* __restrict__ P2,
                                                    unsigned short* __restrict__ P3) {
  __shared__ unsigned short Ks[2][16 * 1024];  // 2 x 32 KB
  __shared__ unsigned short Vs[2][1024 * 16];  // 2 x 32 KB
  __shared__ f32x4 Sx[2][8][64];               // 16 KB f32 partial denominators

  const int combo = blockIdx.x;
  const int b = combo & 1, s = combo >> 1;
  const int qy = 63 - blockIdx.y;
  const int tid = threadIdx.x;
  const int w = tid >> 6, l = tid & 63, g = l >> 4, c = l & 15;
  const int isub = w >> 3, hp = w & 7;
  const float SC = 0.04508422f;  // log2(e)/32
  unsigned short* AOp = s == 0 ? P0 : s == 1 ? P1 : s == 2 ? P2 : P3;

  const int krow0 = tid >> 7, kc8 = tid & 127;
  const int kscc0 = kc8 ^ (krow0 & 7);
  const int krow1 = krow0 + 8;
  const int kscc1 = kc8 ^ (krow1 & 7);
  const unsigned short* kp0 = &Kb[(((size_t)((b << 11) + krow0)) << 10) + (kscc0 << 3)];
  const unsigned short* kp1 = &Kb[(((size_t)((b << 11) + krow1)) << 10) + (kscc1 << 3)];
  const int vd0 = tid >> 1, vjc = tid & 1;
  const int vjo0 = ((vjc << 1) ^ (((vd0 >> 2) & 1) << 1)) << 2;
  const int vd1 = vd0 + 512;
  const int vjo1 = ((vjc << 1) ^ (((vd1 >> 2) & 1) << 1)) << 2;
  const unsigned short* vp0 = &Vt[(((size_t)((b << 10) + vd0)) << 11) + vjo0];
  const unsigned short* vp1 = &Vt[(((size_t)((b << 10) + vd1)) << 11) + vjo1];

#pragma unroll
  for (int ph = 0; ph < 2; ++ph) {
    const int q = ph ? (63 - qy) : qy;
    const int nt16 = (q + 1) << 1;
    const int i0w = (q << 5) + (isub << 4);
    const int ib = i0w + c;

    const unsigned short* qbase =
        &Qb[((size_t)((b << 11) + i0w + c) << 10) + (hp << 7) + (g << 3)];
    bf16x8 qf[4];
    qf[0] = *(const bf16x8*)&qbase[0];
    qf[1] = *(const bf16x8*)&qbase[32];
    qf[2] = *(const bf16x8*)&qbase[64];
    qf[3] = *(const bf16x8*)&qbase[96];

    f32x4 acc[2][4];
#pragma unroll
    for (int hh = 0; hh < 2; ++hh)
#pragma unroll
      for (int cc = 0; cc < 4; ++cc) acc[hh][cc] = {0.f, 0.f, 0.f, 0.f};

#pragma unroll
    for (int e = 0; e < 2; ++e) {
      const int eh = e ? (7 - s) : s;
      const int lo = eh << 4;
      const int hi = (lo + 16) < nt16 ? (lo + 16) : nt16;
      if (lo >= hi) continue;

      {
        const size_t ko = ((size_t)lo << 14);
        gld_lds16(kp0 + ko, &Ks[0][tid << 3]);
        gld_lds16(kp1 + ko, &Ks[0][(tid + 1024) << 3]);
        const int jo = lo << 4;
        gld_lds16(vp0 + jo, &Vs[0][tid << 3]);
        gld_lds16(vp1 + jo, &Vs[0][(tid + 1024) << 3]);
      }
      __syncthreads();

      for (int ts = lo; ts < hi; ++ts) {
        const int cur = (ts - lo) & 1;
        if (ts + 1 < hi) {
          const size_t ko = ((size_t)(ts + 1) << 14);
          gld_lds16(kp0 + ko, &Ks[cur ^ 1][tid << 3]);
          gld_lds16(kp1 + ko, &Ks[cur ^ 1][(tid + 1024) << 3]);
          const int jo = (ts + 1) << 4;
          gld_lds16(vp0 + jo, &Vs[cur ^ 1][tid << 3]);
          gld_lds16(vp1 + jo, &Vs[cur ^ 1][(tid + 1024) << 3]);
        }
        const int j0 = ts << 4;
        const int kx = c & 7;
        f32x4 ex[2];
        f32x4 ps = {0.f, 0.f, 0.f, 0.f};
#pragma unroll
        for (int hh = 0; hh < 2; ++hh) {
          const int hc = ((hp << 1) + hh) << 3;
          const bf16x8 k0 = *(const bf16x8*)&Ks[cur][((c << 7) + ((hc + g) ^ kx)) << 3];
          const bf16x8 k1 = *(const bf16x8*)&Ks[cur][((c << 7) + ((hc + 4 + g) ^ kx)) << 3];
          f32x4 a = {0.f, 0.f, 0.f, 0.f};
          a = __builtin_amdgcn_mfma_f32_16x16x32_bf16(k0, qf[2 * hh], a, 0, 0, 0);
          a = __builtin_amdgcn_mfma_f32_16x16x32_bf16(k1, qf[2 * hh + 1], a, 0, 0, 0);
#pragma unroll
          for (int r = 0; r < 4; ++r) ex[hh][r] = exp2f(a[r] * SC);
          ps += ex[hh];
        }
        Sx[isub][hp][l] = ps;
        // BAR1: fence LDS (Sx) only — staging stays in flight
        asm volatile("s_waitcnt lgkmcnt(0)" ::: "memory");
        __builtin_amdgcn_s_barrier();
        __builtin_amdgcn_sched_barrier(0);
        f32x4 sum = Sx[isub][0][l];
#pragma unroll
        for (int d8 = 1; d8 < 8; ++d8) sum += Sx[isub][d8][l];
        f32x4 inv;
#pragma unroll
        for (int r = 0; r < 4; ++r) inv[r] = __builtin_amdgcn_rcpf(sum[r]);
        float wv[2][4];
        if (j0 + 15 <= i0w) {
#pragma unroll
          for (int hh = 0; hh < 2; ++hh)
#pragma unroll
            for (int r = 0; r < 4; ++r) wv[hh][r] = ex[hh][r] * inv[r];
        } else {
          const int jb = j0 + (g << 2);
#pragma unroll
          for (int hh = 0; hh < 2; ++hh)
#pragma unroll
            for (int r = 0; r < 4; ++r)
              wv[hh][r] = (jb + r > ib) ? 0.0625f : ex[hh][r] * inv[r];
        }
#pragma unroll
        for (int hh = 0; hh < 2; ++hh) {
          union { bf16x4 v; unsigned u[2]; } pa;
          pa.u[0] = pack_bf16(wv[hh][0], wv[hh][1]);
          pa.u[1] = pack_bf16(wv[hh][2], wv[hh][3]);
#pragma unroll
          for (int cc = 0; cc < 4; ++cc) {
            const int d = (((hp << 1) + hh) << 6) + (cc << 4) + c;
            const int up = g ^ (((d >> 2) & 1) << 1);
            union { bf16x4 v; unsigned u[2]; } vf;
            *(uint2*)&vf = *(const uint2*)&Vs[cur][(d << 4) + (up << 2)];
            acc[hh][cc] =
                __builtin_amdgcn_mfma_f32_16x16x16bf16_1k(pa.v, vf.v, acc[hh][cc], 0, 0, 0);
          }
        }
        __syncthreads();  // BAR2: full drain before buffer reuse
      }
    }
#pragma unroll
    for (int hh = 0; hh < 2; ++hh)
#pragma unroll
      for (int cc = 0; cc < 4; ++cc) {
        const int d = (((hp << 1) + hh) << 6) + (cc << 4) + c;
#pragma unroll
        for (int r = 0; r < 4; ++r)
          AOp[((size_t)((b << 11) + i0w + (g << 2) + r) << 10) + d] = f2b(acc[hh][cc][r]);
      }
  }
}

// ---------- sum 4 bf16 partials + (1/16)*suffix -> bf16 ----------
__global__ __launch_bounds__(256) void aocvt(const unsigned short* __restrict__ P0,
                                             const unsigned short* __restrict__ P1,
                                             const unsigned short* __restrict__ P2,
                                             const unsigned short* __restrict__ P3,
                                             const float* __restrict__ Suf,
                                             unsigned short* __restrict__ AOb) {
  const int i = (blockIdx.x * 256 + threadIdx.x) << 3;
  const int m = i >> 10;
  const int b = m >> 11;
  const int sufidx = ((m & 2047) >> 5) + 1;
  const int d0 = i & 1023;
  const float* sp = &Suf[((size_t)(b * 65 + sufidx) << 10) + d0];
  const uint4 v0 = *(const uint4*)&P0[i];
  const uint4 v1 = *(const uint4*)&P1[i];
  const uint4 v2 = *(const uint4*)&P2[i];
  const uint4 v3 = *(const uint4*)&P3[i];
  const float4 s0 = *(const float4*)&sp[0];
  const float4 s1 = *(const float4*)&sp[4];
  uint4 o;
  o.x = pack_bf16(blo(v0.x) + blo(v1.x) + blo(v2.x) + blo(v3.x) + 0.0625f * s0.x,
                  bhi(v0.x) + bhi(v1.x) + bhi(v2.x) + bhi(v3.x) + 0.0625f * s0.y);
  o.y = pack_bf16(blo(v0.y) + blo(v1.y) + blo(v2.y) + blo(v3.y) + 0.0625f * s0.z,
                  bhi(v0.y) + bhi(v1.y) + bhi(v2.y) + bhi(v3.y) + 0.0625f * s0.w);
  o.z = pack_bf16(blo(v0.z) + blo(v1.z) + blo(v2.z) + blo(v3.z) + 0.0625f * s1.x,
                  bhi(v0.z) + bhi(v1.z) + bhi(v2.z) + bhi(v3.z) + 0.0625f * s1.y);
  o.w = pack_bf16(blo(v0.w) + blo(v1.w) + blo(v2.w) + blo(v3.w) + 0.0625f * s1.z,
                  bhi(v0.w) + bhi(v1.w) + bhi(v2.w) + bhi(v3.w) + 0.0625f * s1.w);
  *(uint4*)&AOb[i] = o;
}

extern "C" void kernel_launch(void* const* d_in, const int* in_sizes, int n_in,
                              void* d_out, int out_size, void* d_ws, size_t ws_size,
                              hipStream_t stream) {
  (void)in_sizes; (void)n_in; (void)out_size; (void)ws_size;
  const float* x = (const float*)d_in[0];
  const float* Wq = (const float*)d_in[1];
  const float* bq = (const float*)d_in[2];
  const float* Wk = (const float*)d_in[3];
  const float* bk = (const float*)d_in[4];
  const float* Wv = (const float*)d_in[5];
  const float* bv = (const float*)d_in[6];
  const float* Wo = (const float*)d_in[7];
  const float* bo = (const float*)d_in[8];
  float* out = (float*)d_out;
  char* ws = (char*)d_ws;

  const size_t MB = 1024 * 1024;
  unsigned short* xb  = (unsigned short*)(ws);            // 0-8MB; = AOP0 after projections
  unsigned short* Qb  = (unsigned short*)(ws + 8 * MB);   // 8-16; = AOb after attn
  unsigned short* Kb  = (unsigned short*)(ws + 16 * MB);  // 16-24
  unsigned short* AOP1 = (unsigned short*)(ws + 24 * MB); // 24-32
  unsigned short* Vt  = (unsigned short*)(ws + 32 * MB);  // 32-40
  unsigned short* Wqt = (unsigned short*)(ws + 40 * MB);  // 40-42; Suf overlays after proj
  unsigned short* Wkt = (unsigned short*)(ws + 42 * MB);  // 42-44
  unsigned short* Wvt = (unsigned short*)(ws + 44 * MB);  // 44-46
  unsigned short* Wot = (unsigned short*)(ws + 46 * MB);  // 46-48
  unsigned short* AOP2 = (unsigned short*)(ws + 48 * MB); // 48-56
  unsigned short* AOP3 = (unsigned short*)(ws + 56 * MB); // 56-64
  float* Suf = (float*)(ws + 40 * MB);                    // 532 KB (over dead Wqt)
  unsigned short* AOP0 = xb;
  unsigned short* AOb = Qb;

  hipLaunchKernelGGL(wtrans, dim3(16, 16, 4), dim3(256), 0, stream,
                     Wq, Wk, Wv, Wo, Wqt, Wkt, Wvt, Wot);
  hipLaunchKernelGGL(xconv, dim3(2048), dim3(256), 0, stream, x, xb);
  hipLaunchKernelGGL((gemm_mfma<true>), dim3(8, 32, 2), dim3(256), 0, stream,
                     xb, Wqt, Wkt, Wkt, bq, bk, bk, (void*)Qb, (void*)Kb, (void*)Kb);
  hipLaunchKernelGGL(gemm_vt, dim3(8, 32), dim3(256), 0, stream, xb, Wvt, bv, Vt);
  hipLaunchKernelGGL(vsuf, dim3(8), dim3(256), 0, stream, Vt, Suf);
  hipLaunchKernelGGL(attn_v21, dim3(8, 32), dim3(1024), 0, stream,
                     Qb, Kb, Vt, AOP0, AOP1, AOP2, AOP3);
  hipLaunchKernelGGL(aocvt, dim3(2048), dim3(256), 0, stream,
                     AOP0, AOP1, AOP2, AOP3, Suf, AOb);
  hipLaunchKernelGGL((gemm_mfma<false>), dim3(8, 32, 1), dim3(256), 0, stream,
                     AOb, Wot, Wot, Wot, bo, bo, bo, (void*)out, (void*)out, (void*)out);
}

// Round 22
// 192.969 us; speedup vs baseline: 1.8937x; 1.1206x over previous
//
#include <hip/hip_runtime.h>
#include <hip/hip_bf16.h>

#define B_ 2
#define T_ 2048
#define D_ 1024
#define H_ 16

typedef __attribute__((ext_vector_type(8))) short bf16x8;
typedef __attribute__((ext_vector_type(4))) short bf16x4;
typedef __attribute__((ext_vector_type(4))) float f32x4;

__device__ __forceinline__ unsigned pack_bf16(float x, float y) {
  unsigned xb = __float_as_uint(x), yb = __float_as_uint(y);
  xb += 0x7fffu + ((xb >> 16) & 1u);
  yb += 0x7fffu + ((yb >> 16) & 1u);
  return (xb >> 16) | (yb & 0xffff0000u);
}
__device__ __forceinline__ unsigned short f2b(float x) {
  unsigned u = __float_as_uint(x);
  u += 0x7fffu + ((u >> 16) & 1u);
  return (unsigned short)(u >> 16);
}
__device__ __forceinline__ float blo(unsigned u) { return __uint_as_float(u << 16); }
__device__ __forceinline__ float bhi(unsigned u) { return __uint_as_float(u & 0xffff0000u); }

__device__ __forceinline__ void gld_lds16(const unsigned short* g, unsigned short* l) {
  __builtin_amdgcn_global_load_lds(
      (const __attribute__((address_space(1))) unsigned int*)g,
      (__attribute__((address_space(3))) unsigned int*)l, 16, 0, 0);
}

// ---------- weight transpose + convert: Wt[n][k] = bf16(W[k][n]), 4 weights ----------
__global__ __launch_bounds__(256) void wtrans(const float* __restrict__ W0, const float* __restrict__ W1,
                                              const float* __restrict__ W2, const float* __restrict__ W3,
                                              unsigned short* __restrict__ T0, unsigned short* __restrict__ T1,
                                              unsigned short* __restrict__ T2, unsigned short* __restrict__ T3) {
  const int z = blockIdx.z;
  const float* W = z == 0 ? W0 : z == 1 ? W1 : z == 2 ? W2 : W3;
  unsigned short* T = z == 0 ? T0 : z == 1 ? T1 : z == 2 ? T2 : T3;
  __shared__ unsigned short t[64][72];
  const int k0 = blockIdx.x << 6, n0 = blockIdx.y << 6;
  const int r = threadIdx.x >> 2, c16 = (threadIdx.x & 3) << 4;
#pragma unroll
  for (int e = 0; e < 4; ++e) {
    const float4 v = *(const float4*)&W[(size_t)(k0 + r) * 1024 + n0 + c16 + e * 4];
    t[r][c16 + e * 4 + 0] = f2b(v.x);
    t[r][c16 + e * 4 + 1] = f2b(v.y);
    t[r][c16 + e * 4 + 2] = f2b(v.z);
    t[r][c16 + e * 4 + 3] = f2b(v.w);
  }
  __syncthreads();
  unsigned short o[16];
#pragma unroll
  for (int e = 0; e < 16; ++e) o[e] = t[c16 + e][r];
  unsigned short* dst = &T[(size_t)(n0 + r) * 1024 + k0 + c16];
  *(uint4*)&dst[0] = *(uint4*)&o[0];
  *(uint4*)&dst[8] = *(uint4*)&o[8];
}

// ---------- x fp32 -> bf16 ----------
__global__ __launch_bounds__(256) void xconv(const float* __restrict__ x, unsigned short* __restrict__ xb) {
  const int i = (blockIdx.x * 256 + threadIdx.x) * 8;
  const float4 a = *(const float4*)&x[i];
  const float4 b = *(const float4*)&x[i + 4];
  uint4 o;
  o.x = pack_bf16(a.x, a.y);
  o.y = pack_bf16(a.z, a.w);
  o.z = pack_bf16(b.x, b.y);
  o.w = pack_bf16(b.z, b.w);
  *(uint4*)&xb[i] = o;
}

// ---------- bf16 MFMA GEMM: Y = A[M,1024] @ Bt[n][k]^T + bias ----------
template <bool BF16OUT>
__global__ __launch_bounds__(256) void gemm_mfma(const unsigned short* __restrict__ A,
                                                 const unsigned short* __restrict__ B0,
                                                 const unsigned short* __restrict__ B1,
                                                 const unsigned short* __restrict__ B2,
                                                 const float* __restrict__ bi0, const float* __restrict__ bi1,
                                                 const float* __restrict__ bi2,
                                                 void* __restrict__ Y0, void* __restrict__ Y1,
                                                 void* __restrict__ Y2) {
  const int z = blockIdx.z;
  const unsigned short* Bt = z == 0 ? B0 : z == 1 ? B1 : B2;
  const float* bias = z == 0 ? bi0 : z == 1 ? bi1 : bi2;
  void* Y = z == 0 ? Y0 : z == 1 ? Y1 : Y2;
  __shared__ unsigned short As[8192];
  __shared__ unsigned short Bs[8192];
  const int tid = threadIdx.x;
  const int m0 = blockIdx.y << 7, n0 = blockIdx.x << 7;
  const int w = tid >> 6, l = tid & 63, g = l >> 4, c = l & 15;
  const int wm = (w >> 1) << 6, wn = (w & 1) << 6;
  const int srow = tid >> 3;
  const int skel = ((tid & 7) ^ (srow & 7)) << 3;
  const unsigned short* ga = &A[(size_t)(m0 + srow) * 1024 + skel];
  const unsigned short* gb = &Bt[(size_t)(n0 + srow) * 1024 + skel];
  unsigned short* la = &As[tid << 3];
  unsigned short* lb = &Bs[tid << 3];
  f32x4 acc[4][4];
#pragma unroll
  for (int i = 0; i < 4; ++i)
#pragma unroll
    for (int j = 0; j < 4; ++j) acc[i][j] = {0.f, 0.f, 0.f, 0.f};
  for (int k0 = 0; k0 < 1024; k0 += 64) {
    __syncthreads();
#pragma unroll
    for (int a = 0; a < 4; ++a) {
      gld_lds16(ga + (size_t)(a << 5) * 1024 + k0, la + (a << 11));
      gld_lds16(gb + (size_t)(a << 5) * 1024 + k0, lb + (a << 11));
    }
    __syncthreads();
#pragma unroll
    for (int kc = 0; kc < 2; ++kc) {
      bf16x8 af[4], bfr[4];
#pragma unroll
      for (int mf = 0; mf < 4; ++mf) {
        const int m = wm + (mf << 4) + c;
        af[mf] = *(const bf16x8*)&As[((m << 6) + (kc << 5) + (g << 3)) ^ ((m & 7) << 3)];
      }
#pragma unroll
      for (int nf = 0; nf < 4; ++nf) {
        const int n = wn + (nf << 4) + c;
        bfr[nf] = *(const bf16x8*)&Bs[((n << 6) + (kc << 5) + (g << 3)) ^ ((n & 7) << 3)];
      }
#pragma unroll
      for (int mf = 0; mf < 4; ++mf)
#pragma unroll
        for (int nf = 0; nf < 4; ++nf)
          acc[mf][nf] = __builtin_amdgcn_mfma_f32_16x16x32_bf16(af[mf], bfr[nf], acc[mf][nf], 0, 0, 0);
    }
  }
#pragma unroll
  for (int nf = 0; nf < 4; ++nf) {
    const int n = n0 + wn + (nf << 4) + c;
    const float bb = bias[n];
#pragma unroll
    for (int mf = 0; mf < 4; ++mf) {
      const int mrow = m0 + wm + (mf << 4) + (g << 2);
#pragma unroll
      for (int r = 0; r < 4; ++r) {
        const float val = acc[mf][nf][r] + bb;
        if (BF16OUT)
          ((unsigned short*)Y)[((size_t)(mrow + r) << 10) + n] = f2b(val);
        else
          ((float*)Y)[((size_t)(mrow + r) << 10) + n] = val;
      }
    }
  }
}

// ---------- V-projection GEMM with fused transpose: Vt[b][d][t] written directly ----------
__global__ __launch_bounds__(256) void gemm_vt(const unsigned short* __restrict__ A,
                                               const unsigned short* __restrict__ Bt,
                                               const float* __restrict__ bias,
                                               unsigned short* __restrict__ Vt) {
  __shared__ unsigned short As[8192];
  __shared__ unsigned short Bs[8192];
  __shared__ unsigned short sm[128][136];
  const int tid = threadIdx.x;
  const int m0 = blockIdx.y << 7, n0 = blockIdx.x << 7;
  const int w = tid >> 6, l = tid & 63, g = l >> 4, c = l & 15;
  const int wm = (w >> 1) << 6, wn = (w & 1) << 6;
  const int srow = tid >> 3;
  const int skel = ((tid & 7) ^ (srow & 7)) << 3;
  const unsigned short* ga = &A[(size_t)(m0 + srow) * 1024 + skel];
  const unsigned short* gb = &Bt[(size_t)(n0 + srow) * 1024 + skel];
  unsigned short* la = &As[tid << 3];
  unsigned short* lb = &Bs[tid << 3];
  f32x4 acc[4][4];
#pragma unroll
  for (int i = 0; i < 4; ++i)
#pragma unroll
    for (int j = 0; j < 4; ++j) acc[i][j] = {0.f, 0.f, 0.f, 0.f};
  for (int k0 = 0; k0 < 1024; k0 += 64) {
    __syncthreads();
#pragma unroll
    for (int a = 0; a < 4; ++a) {
      gld_lds16(ga + (size_t)(a << 5) * 1024 + k0, la + (a << 11));
      gld_lds16(gb + (size_t)(a << 5) * 1024 + k0, lb + (a << 11));
    }
    __syncthreads();
#pragma unroll
    for (int kc = 0; kc < 2; ++kc) {
      bf16x8 af[4], bfr[4];
#pragma unroll
      for (int mf = 0; mf < 4; ++mf) {
        const int m = wm + (mf << 4) + c;
        af[mf] = *(const bf16x8*)&As[((m << 6) + (kc << 5) + (g << 3)) ^ ((m & 7) << 3)];
      }
#pragma unroll
      for (int nf = 0; nf < 4; ++nf) {
        const int n = wn + (nf << 4) + c;
        bfr[nf] = *(const bf16x8*)&Bs[((n << 6) + (kc << 5) + (g << 3)) ^ ((n & 7) << 3)];
      }
#pragma unroll
      for (int mf = 0; mf < 4; ++mf)
#pragma unroll
        for (int nf = 0; nf < 4; ++nf)
          acc[mf][nf] = __builtin_amdgcn_mfma_f32_16x16x32_bf16(af[mf], bfr[nf], acc[mf][nf], 0, 0, 0);
    }
  }
  __syncthreads();
#pragma unroll
  for (int nf = 0; nf < 4; ++nf) {
    const int nl = wn + (nf << 4) + c;
    const float bb = bias[n0 + nl];
#pragma unroll
    for (int mf = 0; mf < 4; ++mf) {
      const int ml = wm + (mf << 4) + (g << 2);
      uint2 o;
      o.x = pack_bf16(acc[mf][nf][0] + bb, acc[mf][nf][1] + bb);
      o.y = pack_bf16(acc[mf][nf][2] + bb, acc[mf][nf][3] + bb);
      *(uint2*)&sm[nl][ml] = o;
    }
  }
  __syncthreads();
  const int bb2 = m0 >> 11, mr0 = m0 & 2047;
#pragma unroll
  for (int it = 0; it < 8; ++it) {
    const int u = tid + (it << 8);
    const int ns = u >> 4, mc = (u & 15) << 3;
    *(uint4*)&Vt[(((size_t)((bb2 << 10) + n0 + ns)) << 11) + mr0 + mc] = *(const uint4*)&sm[ns][mc];
  }
}

// ---------- per-32-row block sums of V from Vt ----------
__global__ __launch_bounds__(256) void vblk32t(const unsigned short* __restrict__ Vt,
                                               float* __restrict__ Blk) {
  const int b = blockIdx.x >> 6, t = blockIdx.x & 63;
#pragma unroll
  for (int dd = 0; dd < 4; ++dd) {
    const int d = threadIdx.x + (dd << 8);
    const unsigned short* vr = &Vt[(((size_t)((b << 10) + d)) << 11) + (t << 5)];
    float s = 0.f;
#pragma unroll
    for (int qq = 0; qq < 4; ++qq) {
      const uint2 v0 = *(const uint2*)&vr[qq << 3];
      const uint2 v1 = *(const uint2*)&vr[(qq << 3) + 4];
      s += blo(v0.x) + bhi(v0.x) + blo(v0.y) + bhi(v0.y);
      s += blo(v1.x) + bhi(v1.x) + blo(v1.y) + bhi(v1.y);
    }
    Blk[(((size_t)((b << 6) + t)) << 10) + d] = s;
  }
}

// ---------- suffix over 64 tiles ----------
__global__ __launch_bounds__(256) void vsuffix32(const float* __restrict__ Blk, float* __restrict__ Suf) {
  const int idx = blockIdx.x * 256 + threadIdx.x;
  const int b = idx >> 10, d = idx & 1023;
  float s = 0.f;
  Suf[((size_t)(b * 65 + 64) << 10) + d] = 0.f;
  for (int t = 63; t >= 0; --t) {
    s += Blk[((size_t)((b << 6) + t) << 10) + d];
    Suf[((size_t)(b * 65 + t) << 10) + d] = s;
  }
}

// ---------- attention v22 (= v19): split-barrier double-buffered pipeline ----------
__global__ __launch_bounds__(1024, 4) void attn_v22(const unsigned short* __restrict__ Qb,
                                                    const unsigned short* __restrict__ Kb,
                                                    const unsigned short* __restrict__ Vt,
                                                    unsigned short* __restrict__ P0,
                                                    unsigned short* __restrict__ P1,
                                                    unsigned short* __restrict__ P2,
                                                    unsigned short* __restrict__ P3) {
  __shared__ unsigned short Ks[2][16 * 1024];  // 2 x 32 KB
  __shared__ unsigned short Vs[2][1024 * 16];  // 2 x 32 KB
  __shared__ f32x4 Sx[2][8][64];               // 16 KB f32 partial denominators

  const int combo = blockIdx.x;
  const int b = combo & 1, s = combo >> 1;
  const int qy = 63 - blockIdx.y;
  const int tid = threadIdx.x;
  const int w = tid >> 6, l = tid & 63, g = l >> 4, c = l & 15;
  const int isub = w >> 3, hp = w & 7;
  const float SC = 0.04508422f;  // log2(e)/32
  unsigned short* AOp = s == 0 ? P0 : s == 1 ? P1 : s == 2 ? P2 : P3;

  const int krow0 = tid >> 7, kc8 = tid & 127;
  const int kscc0 = kc8 ^ (krow0 & 7);
  const int krow1 = krow0 + 8;
  const int kscc1 = kc8 ^ (krow1 & 7);
  const unsigned short* kp0 = &Kb[(((size_t)((b << 11) + krow0)) << 10) + (kscc0 << 3)];
  const unsigned short* kp1 = &Kb[(((size_t)((b << 11) + krow1)) << 10) + (kscc1 << 3)];
  const int vd0 = tid >> 1, vjc = tid & 1;
  const int vjo0 = ((vjc << 1) ^ (((vd0 >> 2) & 1) << 1)) << 2;
  const int vd1 = vd0 + 512;
  const int vjo1 = ((vjc << 1) ^ (((vd1 >> 2) & 1) << 1)) << 2;
  const unsigned short* vp0 = &Vt[(((size_t)((b << 10) + vd0)) << 11) + vjo0];
  const unsigned short* vp1 = &Vt[(((size_t)((b << 10) + vd1)) << 11) + vjo1];

#pragma unroll
  for (int ph = 0; ph < 2; ++ph) {
    const int q = ph ? (63 - qy) : qy;
    const int nt16 = (q + 1) << 1;
    const int i0w = (q << 5) + (isub << 4);
    const int ib = i0w + c;

    const unsigned short* qbase =
        &Qb[((size_t)((b << 11) + i0w + c) << 10) + (hp << 7) + (g << 3)];
    bf16x8 qf[4];
    qf[0] = *(const bf16x8*)&qbase[0];
    qf[1] = *(const bf16x8*)&qbase[32];
    qf[2] = *(const bf16x8*)&qbase[64];
    qf[3] = *(const bf16x8*)&qbase[96];

    f32x4 acc[2][4];
#pragma unroll
    for (int hh = 0; hh < 2; ++hh)
#pragma unroll
      for (int cc = 0; cc < 4; ++cc) acc[hh][cc] = {0.f, 0.f, 0.f, 0.f};

#pragma unroll
    for (int e = 0; e < 2; ++e) {
      const int eh = e ? (7 - s) : s;
      const int lo = eh << 4;
      const int hi = (lo + 16) < nt16 ? (lo + 16) : nt16;
      if (lo >= hi) continue;

      {
        const size_t ko = ((size_t)lo << 14);
        gld_lds16(kp0 + ko, &Ks[0][tid << 3]);
        gld_lds16(kp1 + ko, &Ks[0][(tid + 1024) << 3]);
        const int jo = lo << 4;
        gld_lds16(vp0 + jo, &Vs[0][tid << 3]);
        gld_lds16(vp1 + jo, &Vs[0][(tid + 1024) << 3]);
      }
      __syncthreads();

      for (int ts = lo; ts < hi; ++ts) {
        const int cur = (ts - lo) & 1;
        if (ts + 1 < hi) {
          const size_t ko = ((size_t)(ts + 1) << 14);
          gld_lds16(kp0 + ko, &Ks[cur ^ 1][tid << 3]);
          gld_lds16(kp1 + ko, &Ks[cur ^ 1][(tid + 1024) << 3]);
          const int jo = (ts + 1) << 4;
          gld_lds16(vp0 + jo, &Vs[cur ^ 1][tid << 3]);
          gld_lds16(vp1 + jo, &Vs[cur ^ 1][(tid + 1024) << 3]);
        }
        const int j0 = ts << 4;
        const int kx = c & 7;
        f32x4 ex[2];
        f32x4 ps = {0.f, 0.f, 0.f, 0.f};
#pragma unroll
        for (int hh = 0; hh < 2; ++hh) {
          const int hc = ((hp << 1) + hh) << 3;
          const bf16x8 k0 = *(const bf16x8*)&Ks[cur][((c << 7) + ((hc + g) ^ kx)) << 3];
          const bf16x8 k1 = *(const bf16x8*)&Ks[cur][((c << 7) + ((hc + 4 + g) ^ kx)) << 3];
          f32x4 a = {0.f, 0.f, 0.f, 0.f};
          a = __builtin_amdgcn_mfma_f32_16x16x32_bf16(k0, qf[2 * hh], a, 0, 0, 0);
          a = __builtin_amdgcn_mfma_f32_16x16x32_bf16(k1, qf[2 * hh + 1], a, 0, 0, 0);
#pragma unroll
          for (int r = 0; r < 4; ++r) ex[hh][r] = exp2f(a[r] * SC);
          ps += ex[hh];
        }
        Sx[isub][hp][l] = ps;
        // BAR1: fence LDS (Sx) only — staging stays in flight
        asm volatile("s_waitcnt lgkmcnt(0)" ::: "memory");
        __builtin_amdgcn_s_barrier();
        __builtin_amdgcn_sched_barrier(0);
        f32x4 sum = Sx[isub][0][l];
#pragma unroll
        for (int d8 = 1; d8 < 8; ++d8) sum += Sx[isub][d8][l];
        f32x4 inv;
#pragma unroll
        for (int r = 0; r < 4; ++r) inv[r] = __builtin_amdgcn_rcpf(sum[r]);
        float wv[2][4];
        if (j0 + 15 <= i0w) {
#pragma unroll
          for (int hh = 0; hh < 2; ++hh)
#pragma unroll
            for (int r = 0; r < 4; ++r) wv[hh][r] = ex[hh][r] * inv[r];
        } else {
          const int jb = j0 + (g << 2);
#pragma unroll
          for (int hh = 0; hh < 2; ++hh)
#pragma unroll
            for (int r = 0; r < 4; ++r)
              wv[hh][r] = (jb + r > ib) ? 0.0625f : ex[hh][r] * inv[r];
        }
#pragma unroll
        for (int hh = 0; hh < 2; ++hh) {
          union { bf16x4 v; unsigned u[2]; } pa;
          pa.u[0] = pack_bf16(wv[hh][0], wv[hh][1]);
          pa.u[1] = pack_bf16(wv[hh][2], wv[hh][3]);
#pragma unroll
          for (int cc = 0; cc < 4; ++cc) {
            const int d = (((hp << 1) + hh) << 6) + (cc << 4) + c;
            const int up = g ^ (((d >> 2) & 1) << 1);
            union { bf16x4 v; unsigned u[2]; } vf;
            *(uint2*)&vf = *(const uint2*)&Vs[cur][(d << 4) + (up << 2)];
            acc[hh][cc] =
                __builtin_amdgcn_mfma_f32_16x16x16bf16_1k(pa.v, vf.v, acc[hh][cc], 0, 0, 0);
          }
        }
        __syncthreads();  // BAR2: full drain before buffer reuse
      }
    }
#pragma unroll
    for (int hh = 0; hh < 2; ++hh)
#pragma unroll
      for (int cc = 0; cc < 4; ++cc) {
        const int d = (((hp << 1) + hh) << 6) + (cc << 4) + c;
#pragma unroll
        for (int r = 0; r < 4; ++r)
          AOp[((size_t)((b << 11) + i0w + (g << 2) + r) << 10) + d] = f2b(acc[hh][cc][r]);
      }
  }
}

// ---------- sum 4 bf16 partials + (1/16)*suffix -> bf16 ----------
__global__ __launch_bounds__(256) void aocvt(const unsigned short* __restrict__ P0,
                                             const unsigned short* __restrict__ P1,
                                             const unsigned short* __restrict__ P2,
                                             const unsigned short* __restrict__ P3,
                                             const float* __restrict__ Suf,
                                             unsigned short* __restrict__ AOb) {
  const int i = (blockIdx.x * 256 + threadIdx.x) << 3;
  const int m = i >> 10;
  const int b = m >> 11;
  const int sufidx = ((m & 2047) >> 5) + 1;
  const int d0 = i & 1023;
  const float* sp = &Suf[((size_t)(b * 65 + sufidx) << 10) + d0];
  const uint4 v0 = *(const uint4*)&P0[i];
  const uint4 v1 = *(const uint4*)&P1[i];
  const uint4 v2 = *(const uint4*)&P2[i];
  const uint4 v3 = *(const uint4*)&P3[i];
  const float4 s0 = *(const float4*)&sp[0];
  const float4 s1 = *(const float4*)&sp[4];
  uint4 o;
  o.x = pack_bf16(blo(v0.x) + blo(v1.x) + blo(v2.x) + blo(v3.x) + 0.0625f * s0.x,
                  bhi(v0.x) + bhi(v1.x) + bhi(v2.x) + bhi(v3.x) + 0.0625f * s0.y);
  o.y = pack_bf16(blo(v0.y) + blo(v1.y) + blo(v2.y) + blo(v3.y) + 0.0625f * s0.z,
                  bhi(v0.y) + bhi(v1.y) + bhi(v2.y) + bhi(v3.y) + 0.0625f * s0.w);
  o.z = pack_bf16(blo(v0.z) + blo(v1.z) + blo(v2.z) + blo(v3.z) + 0.0625f * s1.x,
                  bhi(v0.z) + bhi(v1.z) + bhi(v2.z) + bhi(v3.z) + 0.0625f * s1.y);
  o.w = pack_bf16(blo(v0.w) + blo(v1.w) + blo(v2.w) + blo(v3.w) + 0.0625f * s1.z,
                  bhi(v0.w) + bhi(v1.w) + bhi(v2.w) + bhi(v3.w) + 0.0625f * s1.w);
  *(uint4*)&AOb[i] = o;
}

extern "C" void kernel_launch(void* const* d_in, const int* in_sizes, int n_in,
                              void* d_out, int out_size, void* d_ws, size_t ws_size,
                              hipStream_t stream) {
  (void)in_sizes; (void)n_in; (void)out_size; (void)ws_size;
  const float* x = (const float*)d_in[0];
  const float* Wq = (const float*)d_in[1];
  const float* bq = (const float*)d_in[2];
  const float* Wk = (const float*)d_in[3];
  const float* bk = (const float*)d_in[4];
  const float* Wv = (const float*)d_in[5];
  const float* bv = (const float*)d_in[6];
  const float* Wo = (const float*)d_in[7];
  const float* bo = (const float*)d_in[8];
  float* out = (float*)d_out;
  char* ws = (char*)d_ws;

  const size_t MB = 1024 * 1024;
  unsigned short* xb  = (unsigned short*)(ws);            // 0-8MB; = AOP0 after projections
  unsigned short* Qb  = (unsigned short*)(ws + 8 * MB);   // 8-16; = AOb after attn
  unsigned short* Kb  = (unsigned short*)(ws + 16 * MB);  // 16-24
  unsigned short* AOP1 = (unsigned short*)(ws + 24 * MB); // 24-32
  unsigned short* Vt  = (unsigned short*)(ws + 32 * MB);  // 32-40
  unsigned short* Wqt = (unsigned short*)(ws + 40 * MB);  // 40-42; Blk/Suf overlay after proj
  unsigned short* Wkt = (unsigned short*)(ws + 42 * MB);  // 42-44
  unsigned short* Wvt = (unsigned short*)(ws + 44 * MB);  // 44-46
  unsigned short* Wot = (unsigned short*)(ws + 46 * MB);  // 46-48
  unsigned short* AOP2 = (unsigned short*)(ws + 48 * MB); // 48-56
  unsigned short* AOP3 = (unsigned short*)(ws + 56 * MB); // 56-64
  float* Blk = (float*)(ws + 40 * MB);
  float* Suf = (float*)(ws + 40 * MB + 512 * 1024);
  unsigned short* AOP0 = xb;
  unsigned short* AOb = Qb;

  hipLaunchKernelGGL(wtrans, dim3(16, 16, 4), dim3(256), 0, stream,
                     Wq, Wk, Wv, Wo, Wqt, Wkt, Wvt, Wot);
  hipLaunchKernelGGL(xconv, dim3(2048), dim3(256), 0, stream, x, xb);
  hipLaunchKernelGGL((gemm_mfma<true>), dim3(8, 32, 2), dim3(256), 0, stream,
                     xb, Wqt, Wkt, Wkt, bq, bk, bk, (void*)Qb, (void*)Kb, (void*)Kb);
  hipLaunchKernelGGL(gemm_vt, dim3(8, 32), dim3(256), 0, stream, xb, Wvt, bv, Vt);
  hipLaunchKernelGGL(vblk32t, dim3(128), dim3(256), 0, stream, Vt, Blk);
  hipLaunchKernelGGL(vsuffix32, dim3(8), dim3(256), 0, stream, Blk, Suf);
  hipLaunchKernelGGL(attn_v22, dim3(8, 32), dim3(1024), 0, stream,
                     Qb, Kb, Vt, AOP0, AOP1, AOP2, AOP3);
  hipLaunchKernelGGL(aocvt, dim3(2048), dim3(256), 0, stream,
                     AOP0, AOP1, AOP2, AOP3, Suf, AOb);
  hipLaunchKernelGGL((gemm_mfma<false>), dim3(8, 32, 1), dim3(256), 0, stream,
                     AOb, Wot, Wot, Wot, bo, bo, bo, (void*)out, (void*)out, (void*)out);
}